// Round 16
// baseline (142.479 us; speedup 1.0000x reference)
//
#include <hip/hip_runtime.h>
#include <hip/hip_bf16.h>
#include <stdint.h>

typedef float f32x2 __attribute__((ext_vector_type(2)));
typedef float f32x4 __attribute__((ext_vector_type(4)));
typedef short bf16x8 __attribute__((ext_vector_type(8)));
typedef unsigned int u32;

#define WLDS 20992      // bytes/wave: slab 19840 + a2s 1024 + ccs 128

__device__ __forceinline__ f32x4 leaky4(f32x4 v) {
    return __builtin_elementwise_max(v, v * 0.01f);
}
__device__ __forceinline__ u32 pkbf(float a, float b) {
    union { __hip_bfloat162 h; u32 u; } c;
    c.h = __float22bfloat162_rn(make_float2(a, b));   // a -> low, b -> high
    return c.u;
}
__device__ __forceinline__ short bf1(float a) {
    union { __hip_bfloat16 h; short s; } c;
    c.h = __float2bfloat16(a);
    return c.s;
}
// global->LDS direct, 16 B/lane; ALL sources here are 16B-aligned (flat slab).
__device__ __forceinline__ void gload16(const float* g, void* l) {
    auto gp = reinterpret_cast<const float __attribute__((address_space(1)))*>(
        reinterpret_cast<uintptr_t>(g));
    auto lp = reinterpret_cast<float __attribute__((address_space(3)))*>(
        reinterpret_cast<uintptr_t>(l));
    __builtin_amdgcn_global_load_lds(gp, lp, 16, 0, 0);
}
// Stage one 16-row slab flat: 4960 floats = 19 full w16 + 96-float tail.
__device__ __forceinline__ void stage_slab(const float* src, float* dst, int lane) {
    #pragma unroll
    for (int i = 0; i < 19; ++i) gload16(src + i * 256 + lane * 4, dst + i * 256);
    if (lane < 24) gload16(src + 4864 + lane * 4, dst + 4864);
}

// One wave = 16 rows end-to-end; no barriers; per-wave slab + reg A-frags.
__global__ __launch_bounds__(128) void gen_mlp_r16(
    const float* __restrict__ x, const float* __restrict__ data_t,
    const float* __restrict__ W1, const float* __restrict__ b1,
    const float* __restrict__ W2, const float* __restrict__ b2,
    const float* __restrict__ W3, const float* __restrict__ b3,
    float* __restrict__ out)
{
    __shared__ char smem[2 * WLDS];

    const int tid  = threadIdx.x;
    const int wv   = tid >> 6;
    const int lane = tid & 63;
    const int g    = lane >> 4;         // k-octet group / C row-quad
    const int j    = lane & 15;         // A-row / B-col / C-col
    const int jc   = (j < 10) ? j : 9;

    char*  ws   = smem + wv * WLDS;
    float* slab = (float*)ws;                 // [16 rows][310 k] flat
    char*  a2sb = ws + 19840;                 // [16 rows][32 k] bf16 transpose scratch
    f32x2* ccs  = (f32x2*)(ws + 20864);       // (c0,c1) per row

    // zero A2 scratch once; cols 10..31 stay zero (K-padding for L2)
    *(f32x4*)(a2sb + lane * 16) = (f32x4){0.f, 0.f, 0.f, 0.f};

    // ---- one-time per-wave weight fragments (registers; R11-verified) ----
    bf16x8 w1f[10];
    #pragma unroll
    for (int s = 0; s < 10; ++s) {
        union { u32 d[4]; bf16x8 f; } u;
        #pragma unroll
        for (int e2 = 0; e2 < 4; ++e2) {
            const int k0 = 32 * s + 8 * g + 2 * e2;
            const float va = (k0     < 310 && j < 10) ? W1[k0 * 10 + jc]       : 0.f;
            const float vb = (k0 + 1 < 310 && j < 10) ? W1[(k0 + 1) * 10 + jc] : 0.f;
            u.d[e2] = pkbf(va, vb);
        }
        w1f[s] = u.f;
    }
    bf16x8 w2f[8];
    #pragma unroll
    for (int n = 0; n < 8; ++n) {
        union { u32 d[4]; bf16x8 f; } u;
        #pragma unroll
        for (int e2 = 0; e2 < 4; ++e2) {
            const int k0 = 8 * g + 2 * e2;
            const float va = (k0     < 10) ? W2[k0 * 128 + 16 * n + j]       : 0.f;
            const float vb = (k0 + 1 < 10) ? W2[(k0 + 1) * 128 + 16 * n + j] : 0.f;
            u.d[e2] = pkbf(va, vb);
        }
        w2f[n] = u.f;
    }
    f32x2 w3v[8]; float b2v[8];
    #pragma unroll
    for (int n = 0; n < 8; ++n) {
        w3v[n] = *(const f32x2*)(W3 + (16 * n + j) * 2);
        b2v[n] = b2[16 * n + j];
    }
    const float b1v = b1[jc];
    const float b30 = b3[0], b31 = b3[1];

    const int gw = blockIdx.x * 2 + wv;       // 0..4095; 2 tiles each

    // ---- prologue: stage this wave's first slab ----
    stage_slab(x + (size_t)(gw * 2) * 4960, slab, lane);
    asm volatile("s_waitcnt vmcnt(0)" ::: "memory");

    #pragma unroll 1
    for (int tt = 0; tt < 2; ++tt) {
        const int t = gw * 2 + tt;            // 0..8191
        if (tt > 0)   // drain this slab's 20 stage ops; keep prior stores (7)
            asm volatile("s_waitcnt vmcnt(7)" ::: "memory");

        // ---- A-frags: 10 steps x 4 ds_read_b64 from my row, cvt to bf16 ----
        bf16x8 af[10];
        {
            const float* xr = slab + j * 310 + 8 * g;
            #pragma unroll
            for (int s = 0; s < 10; ++s) {
                // s=9,j=15 overruns into a2s scratch (finite) * zero-W: harmless
                f32x2 p0 = *(const f32x2*)(xr + 32 * s + 0);
                f32x2 p1 = *(const f32x2*)(xr + 32 * s + 2);
                f32x2 p2 = *(const f32x2*)(xr + 32 * s + 4);
                f32x2 p3 = *(const f32x2*)(xr + 32 * s + 6);
                union { u32 d[4]; bf16x8 f; } a;
                a.d[0] = pkbf(p0.x, p0.y); a.d[1] = pkbf(p1.x, p1.y);
                a.d[2] = pkbf(p2.x, p2.y); a.d[3] = pkbf(p3.x, p3.y);
                af[s] = a.f;
            }
        }

        // ---- tv loads BEFORE staging: their consumption wait won't drain stages
        const f32x4* dt4 = (const f32x4*)data_t + (size_t)t * 400;
        f32x4 tv[6];
        #pragma unroll
        for (int q = 0; q < 6; ++q) tv[q] = dt4[lane + 64 * q];
        f32x4 tvL;
        if (lane < 16) tvL = dt4[384 + lane];

        // ---- all slab reads drained -> re-stage same buffer with next slab ----
        asm volatile("s_waitcnt lgkmcnt(0)" ::: "memory");
        if (tt == 0)
            stage_slab(x + (size_t)(t + 1) * 4960, slab, lane);  // in flight across compute

        // ---- L1: 10 MFMAs, weights resident in VGPRs ----
        f32x4 acc = {0.f, 0.f, 0.f, 0.f};
        #pragma unroll
        for (int s = 0; s < 10; ++s)
            acc = __builtin_amdgcn_mfma_f32_16x16x32_bf16(af[s], w1f[s], acc, 0, 0, 0);

        // ---- h1 = leaky(acc + b1) -> per-wave transpose scratch (bf16) ----
        const f32x4 h1 = leaky4(acc + b1v);     // lane: col j, rows 4g+r
        if (j < 10) {
            #pragma unroll
            for (int r = 0; r < 4; ++r)
                *(short*)(a2sb + (4 * g + r) * 64 + j * 2) = bf1(h1[r]);
        }

        // ---- L2 (8 MFMAs) fused with L3 partials ----
        const bf16x8 a2f = *(const bf16x8*)(a2sb + j * 64 + g * 16);
        f32x4 c0a = {0.f, 0.f, 0.f, 0.f}, c1a = {0.f, 0.f, 0.f, 0.f};
        #pragma unroll
        for (int n = 0; n < 8; ++n) {
            const f32x4 z = {0.f, 0.f, 0.f, 0.f};
            f32x4 c2 = __builtin_amdgcn_mfma_f32_16x16x32_bf16(a2f, w2f[n], z, 0, 0, 0);
            f32x4 h2 = leaky4(c2 + b2v[n]);     // rows 4g+r, neuron 16n+j
            c0a += h2 * w3v[n].x;
            c1a += h2 * w3v[n].y;
        }
        #pragma unroll
        for (int m = 1; m <= 8; m <<= 1) {      // reduce over the 16 j-lanes
            #pragma unroll
            for (int r = 0; r < 4; ++r) {
                c0a[r] += __shfl_xor(c0a[r], m, 64);
                c1a[r] += __shfl_xor(c1a[r], m, 64);
            }
        }
        const f32x4 cc0 = leaky4(c0a + b30);
        const f32x4 cc1 = leaky4(c1a + b31);
        if (j == 0) {
            #pragma unroll
            for (int r = 0; r < 4; ++r)
                ccs[4 * g + r] = (f32x2){cc0[r], cc1[r]};
        }

        // ---- epilogue: out = t*(c0 + c1*t), coalesced f32x4 over 16 rows ----
        f32x4* o4 = (f32x4*)out + (size_t)t * 400;
        #pragma unroll
        for (int q = 0; q < 6; ++q) {
            const int idx = lane + 64 * q;
            const f32x2 cc = ccs[idx / 25];
            o4[idx] = tv[q] * (tv[q] * cc.y + cc.x);
        }
        if (lane < 16) {
            const int idx = 384 + lane;
            const f32x2 cc = ccs[idx / 25];
            o4[idx] = tvL * (tvL * cc.y + cc.x);
        }
    }
}

extern "C" void kernel_launch(void* const* d_in, const int* in_sizes, int n_in,
                              void* d_out, int out_size, void* d_ws, size_t ws_size,
                              hipStream_t stream) {
    const float* x      = (const float*)d_in[0];
    const float* data_t = (const float*)d_in[1];
    const float* W1     = (const float*)d_in[2];
    const float* b1     = (const float*)d_in[3];
    const float* W2     = (const float*)d_in[4];
    const float* b2     = (const float*)d_in[5];
    const float* W3     = (const float*)d_in[6];
    const float* b3     = (const float*)d_in[7];
    float* out = (float*)d_out;

    // 2048 blocks x 2 waves x 2 tiles x 16 rows = 131072 rows; no barriers.
    // Static LDS 41,984 B -> 3 blocks/CU = 6 autonomous waves/CU.
    gen_mlp_r16<<<2048, 128, 0, stream>>>(x, data_t, W1, b1, W2, b2, W3, b3, out);
}

// Round 17
// 56.427 us; speedup vs baseline: 2.5250x; 2.5250x over previous
//
#include <hip/hip_runtime.h>
#include <stdint.h>

typedef float f32x2 __attribute__((ext_vector_type(2)));
typedef float f32x4 __attribute__((ext_vector_type(4)));

#define TILE_F 19840      // 64 rows x 310 floats
#define NTPB   4          // tiles per block
#define PSTR   162        // partials [row][16 slots x 10]: 162%32=2 -> 16 banks
#define CP_OFF 10368      // = 64*PSTR; coeff partials [10368, 12544)
#define CPSTR  34         // 34%32=2 -> 16 banks; 16 f32x2 fit (32<=34)
#define A_F    12544      // A region [0,12544): scratch-aliased, staged late
#define APW    784        // A floats/wave-16th: 3 full w16 + 16-float tail
#define BPW    456        // B floats/wave-16th: 1 full w16 + 200-float tail
#define LDSF   (TILE_F + 128)
#define LDS_BYTES (LDSF * 4)    // 79,872 B -> 2 blocks/CU (32 waves/CU)

__device__ __forceinline__ float leaky(float v) { return fmaxf(v, 0.01f * v); }
__device__ __forceinline__ f32x2 leaky2(f32x2 v) {
    return __builtin_elementwise_max(v, v * 0.01f);
}

// global->LDS direct, 16 B/lane; side-effecting (cannot be sunk past the
// volatile waitcnt/barrier asm). All sources 16B-aligned (flat tile).
__device__ __forceinline__ void gload16(const float* g, float* l) {
    auto gp = reinterpret_cast<const float __attribute__((address_space(1)))*>(
        reinterpret_cast<uintptr_t>(g));
    auto lp = reinterpret_cast<float __attribute__((address_space(3)))*>(
        reinterpret_cast<uintptr_t>(l));
    __builtin_amdgcn_global_load_lds(gp, lp, 16, 0, 0);
}

// Region A: 784 floats/wave = 3 full w16 + 16-float tail (4 lanes)
__device__ __forceinline__ void stage_A(const float* src, float* dst, int lane) {
    #pragma unroll
    for (int i = 0; i < 3; ++i) gload16(src + i * 256, dst + i * 256);
    if (lane < 4) gload16(src + 768, dst + 768);
}
// Region B: 456 floats/wave = 1 full w16 + 200-float tail (50 lanes)
__device__ __forceinline__ void stage_B(const float* src, float* dst, int lane) {
    gload16(src, dst);
    if (lane < 50) gload16(src + 256, dst + 256);
}

// FMA of KQ k's (xk in VGPRs) vs W1 slice broadcast from SGPRs (s_load).
template<int KQ>
__device__ __forceinline__ void fma_xk(const float* xk, const float* __restrict__ Wb,
                                       float* acc) {
    #pragma unroll
    for (int k = 0; k < KQ; ++k) {
        #pragma unroll
        for (int j = 0; j < 10; ++j)
            acc[j] = fmaf(xk[k], Wb[k * 10 + j], acc[j]);
    }
}

__global__ __launch_bounds__(1024, 8) void gen_mlp_r17(
    const float* __restrict__ x, const float* __restrict__ data_t,
    const float* __restrict__ W1, const float* __restrict__ b1,
    const float* __restrict__ W2, const float* __restrict__ b2,
    const float* __restrict__ W3, const float* __restrict__ b3,
    float* __restrict__ out)
{
    extern __shared__ float lds[];
    float* buf = lds;                 // x tile; A-region doubles as scratch
    float* ccs = lds + TILE_F;        // 128 floats: final (c0,c1) per row

    const int t    = threadIdx.x;
    const int lane = t & 63;
    const int row  = lane;                                    // lane = row
    const int wq   = __builtin_amdgcn_readfirstlane(t >> 6);  // wave 0..15

    const int tile0 = blockIdx.x * NTPB;

    // ---- prologue: stage tile0 fully (6 async ops/wave, zero VGPR) ----
    {
        const float* g = x + (size_t)tile0 * TILE_F;
        stage_A(g + wq * APW + lane * 4,       buf + wq * APW,       lane);
        stage_B(g + A_F + wq * BPW + lane * 4, buf + A_F + wq * BPW, lane);
    }
    asm volatile("s_waitcnt vmcnt(0)" ::: "memory");
    __builtin_amdgcn_s_barrier();

    #pragma unroll 1
    for (int it = 0; it < NTPB; ++it) {
        const int tile  = tile0 + it;
        // unconditional staging (static vm-op counts); last iter re-stages
        // tile0 (L3-warm, harmless).
        const int tnext = (it + 1 < NTPB) ? tile + 1 : tile0;
        const float* gnext = x + (size_t)tnext * TILE_F;

        // ---- data_t loads FIRST (oldest vm ops of the iteration) ----
        const f32x4* dt4 = (const f32x4*)data_t + (size_t)tile * 1600;
        f32x4 tv0 = dt4[t], tv1;
        if (t < 576) tv1 = dt4[1024 + t];      // uniform per wave (576 = 9*64)

        // ---- x: my k-sixteenth -> registers ----
        float xk[20];
        {
            const float* xr = buf + row * 310 + wq * 20;
            if (wq == 15) {
                #pragma unroll
                for (int q = 0; q < 5; ++q)
                    *(f32x2*)&xk[2 * q] = *(const f32x2*)(xr + 2 * q);
            } else {
                #pragma unroll
                for (int q = 0; q < 10; ++q)
                    *(f32x2*)&xk[2 * q] = *(const f32x2*)(xr + 2 * q);
            }
        }
        asm volatile("s_waitcnt lgkmcnt(0)" ::: "memory");
        __builtin_amdgcn_s_barrier();     // (a0): buf free (x lives in regs)

        // ---- stage next tile's B region (not scratch-aliased) ----
        stage_B(gnext + A_F + wq * BPW + lane * 4, buf + A_F + wq * BPW, lane);

        // ---- L1: my k-sixteenth, weights via s_load (SGPR broadcast) ----
        float acc[10] = {0,0,0,0,0,0,0,0,0,0};
        if (wq == 15) fma_xk<10>(xk, W1 + 3000, acc);
        else          fma_xk<20>(xk, W1 + wq * 200, acc);

        {   // ---- partials [row][wq][10] into A-region scratch ----
            float* pw = buf + row * PSTR + wq * 10;
            #pragma unroll
            for (int j = 0; j < 5; ++j)
                *(f32x2*)(pw + 2 * j) = (f32x2){acc[2 * j], acc[2 * j + 1]};
        }
        asm volatile("s_waitcnt lgkmcnt(0)" ::: "memory");
        __builtin_amdgcn_s_barrier();     // (a)

        // ---- pairwise pre-reduce: slot wq += slot wq+8 (waves 0-7) ----
        if (wq < 8) {
            float* pr = buf + row * PSTR + wq * 10;
            const float* ph = buf + row * PSTR + (wq + 8) * 10;
            #pragma unroll
            for (int m = 0; m < 5; ++m) {
                f32x2 v = *(const f32x2*)(pr + 2 * m) + *(const f32x2*)(ph + 2 * m);
                *(f32x2*)(pr + 2 * m) = v;
            }
        }
        asm volatile("s_waitcnt lgkmcnt(0)" ::: "memory");
        __builtin_amdgcn_s_barrier();     // (a2)

        // ---- h1 = leaky(sum of 8 pre-reduced slots + b1) ----
        float h1[10];
        {
            const float* pr = buf + row * PSTR;
            float s[10];
            #pragma unroll
            for (int j = 0; j < 10; ++j) s[j] = b1[j];
            #pragma unroll
            for (int sl = 0; sl < 8; ++sl) {
                #pragma unroll
                for (int m = 0; m < 5; ++m) {
                    f32x2 v = *(const f32x2*)(pr + sl * 10 + 2 * m);
                    s[2 * m]     += v.x;
                    s[2 * m + 1] += v.y;
                }
            }
            #pragma unroll
            for (int j = 0; j < 10; ++j) h1[j] = leaky(s[j]);
        }

        // ---- L2 j-slice (8 outs) + L3 partial; weights via s_load ----
        float hh[8];
        #pragma unroll
        for (int jj = 0; jj < 8; ++jj) hh[jj] = b2[wq * 8 + jj];
        #pragma unroll
        for (int k = 0; k < 10; ++k) {
            #pragma unroll
            for (int jj = 0; jj < 8; ++jj)
                hh[jj] = fmaf(h1[k], W2[k * 128 + wq * 8 + jj], hh[jj]);
        }
        f32x2 p = {0.f, 0.f};
        #pragma unroll
        for (int jj = 0; jj < 8; ++jj) {
            const float s = leaky(hh[jj]);
            p.x = fmaf(s, W3[(wq * 8 + jj) * 2 + 0], p.x);
            p.y = fmaf(s, W3[(wq * 8 + jj) * 2 + 1], p.y);
        }

        // ---- coeff partials [row][34] at CP_OFF ----
        *(f32x2*)(buf + CP_OFF + row * CPSTR + 2 * wq) = p;
        asm volatile("s_waitcnt lgkmcnt(0)" ::: "memory");
        __builtin_amdgcn_s_barrier();     // (b)

        if (wq == 0) {   // 16 x b64 reads, 16-bank spread
            const float* cb = buf + CP_OFF + row * CPSTR;
            f32x2 q = {b3[0], b3[1]};
            #pragma unroll
            for (int i = 0; i < 16; ++i) {
                f32x2 v = *(const f32x2*)(cb + 2 * i);
                q.x += v.x;
                q.y += v.y;
            }
            *(f32x2*)(ccs + 2 * row) = leaky2(q);
        }
        asm volatile("s_waitcnt lgkmcnt(0)" ::: "memory");
        __builtin_amdgcn_s_barrier();     // (b2): ccs ready, A-scratch dead

        // ---- stage next tile's A region (scratch dead now) ----
        stage_A(gnext + wq * APW + lane * 4, buf + wq * APW, lane);

        // ---- epilogue: out = t*(c0 + c1*t) ----
        f32x4* o4 = (f32x4*)out + (size_t)tile * 1600;
        {
            f32x2 cc = *(const f32x2*)(ccs + 2 * (t / 25));
            o4[t] = tv0 * (tv0 * cc.y + cc.x);
        }
        if (t < 576) {
            const int idx = 1024 + t;
            f32x2 cc = *(const f32x2*)(ccs + 2 * (idx / 25));
            o4[idx] = tv1 * (tv1 * cc.y + cc.x);
        }

        // ---- (d): all 6 staging ops of tile it+1 retired; 1 store rides ----
        asm volatile("s_waitcnt vmcnt(1)" ::: "memory");
        __builtin_amdgcn_s_barrier();
    }
}

extern "C" void kernel_launch(void* const* d_in, const int* in_sizes, int n_in,
                              void* d_out, int out_size, void* d_ws, size_t ws_size,
                              hipStream_t stream) {
    const float* x      = (const float*)d_in[0];
    const float* data_t = (const float*)d_in[1];
    const float* W1     = (const float*)d_in[2];
    const float* b1     = (const float*)d_in[3];
    const float* W2     = (const float*)d_in[4];
    const float* b2     = (const float*)d_in[5];
    const float* W3     = (const float*)d_in[6];
    const float* b3     = (const float*)d_in[7];
    float* out = (float*)d_out;

    hipFuncSetAttribute((const void*)gen_mlp_r17,
                        hipFuncAttributeMaxDynamicSharedMemorySize, LDS_BYTES);
    // 512 blocks x 1024 threads (16 waves) x 4 tiles of 64 rows = 131072 rows;
    // 2 blocks/CU = 32 waves/CU (occupancy max).
    gen_mlp_r17<<<512, 1024, LDS_BYTES, stream>>>(x, data_t, W1, b1, W2, b2, W3, b3, out);
}

// Round 18
// 51.866 us; speedup vs baseline: 2.7471x; 1.0879x over previous
//
#include <hip/hip_runtime.h>
#include <stdint.h>

typedef float f32x2 __attribute__((ext_vector_type(2)));
typedef float f32x4 __attribute__((ext_vector_type(4)));

#define TILE_F 19840      // 64 rows x 310 floats
#define NTPB   4          // tiles per block
#define PSTR   162        // partials [row][16 slots x 10]: 162%32=2 -> 16 banks
#define CP_OFF 10368      // = 64*PSTR; coeff partials [10368, 12544)
#define CPSTR  34         // 34%32=2 -> 16 banks
#define H1_OFF 12544      // h1 [row][14]: [12544, 13440)
#define H1STR  14         // 14%32 -> 16 banks; even -> b64-aligned
#define A_F    13440      // A region [0,13440): scratch-aliased, staged late
#define APW    840        // A floats/wave-16th: 3 full w16 + 72-float tail
#define BPW    400        // B floats/wave-16th: 1 full w16 + 144-float tail
#define LDSF   (TILE_F + 128)
#define LDS_BYTES (LDSF * 4)    // 79,872 B -> 2 blocks/CU (32 waves/CU)

__device__ __forceinline__ float leaky(float v) { return fmaxf(v, 0.01f * v); }
__device__ __forceinline__ f32x2 leaky2(f32x2 v) {
    return __builtin_elementwise_max(v, v * 0.01f);
}

// global->LDS direct, 16 B/lane; side-effecting (cannot be sunk past the
// volatile waitcnt/barrier asm). All sources 16B-aligned (flat tile).
__device__ __forceinline__ void gload16(const float* g, float* l) {
    auto gp = reinterpret_cast<const float __attribute__((address_space(1)))*>(
        reinterpret_cast<uintptr_t>(g));
    auto lp = reinterpret_cast<float __attribute__((address_space(3)))*>(
        reinterpret_cast<uintptr_t>(l));
    __builtin_amdgcn_global_load_lds(gp, lp, 16, 0, 0);
}

// Region A: 840 floats/wave = 3 full w16 + 72-float tail (18 lanes)
__device__ __forceinline__ void stage_A(const float* src, float* dst, int lane) {
    #pragma unroll
    for (int i = 0; i < 3; ++i) gload16(src + i * 256, dst + i * 256);
    if (lane < 18) gload16(src + 768, dst + 768);
}
// Region B: 400 floats/wave = 1 full w16 + 144-float tail (36 lanes)
__device__ __forceinline__ void stage_B(const float* src, float* dst, int lane) {
    gload16(src, dst);
    if (lane < 36) gload16(src + 256, dst + 256);
}

// FMA of KQ k's (xk in VGPRs) vs W1 slice broadcast from SGPRs (s_load).
template<int KQ>
__device__ __forceinline__ void fma_xk(const float* xk, const float* __restrict__ Wb,
                                       float* acc) {
    #pragma unroll
    for (int k = 0; k < KQ; ++k) {
        #pragma unroll
        for (int j = 0; j < 10; ++j)
            acc[j] = fmaf(xk[k], Wb[k * 10 + j], acc[j]);
    }
}

__global__ __launch_bounds__(1024, 8) void gen_mlp_r18(
    const float* __restrict__ x, const float* __restrict__ data_t,
    const float* __restrict__ W1, const float* __restrict__ b1,
    const float* __restrict__ W2, const float* __restrict__ b2,
    const float* __restrict__ W3, const float* __restrict__ b3,
    float* __restrict__ out)
{
    extern __shared__ float lds[];
    float* buf = lds;                 // x tile; A-region doubles as scratch
    float* ccs = lds + TILE_F;        // 128 floats: final (c0,c1) per row

    const int t    = threadIdx.x;
    const int lane = t & 63;
    const int row  = lane;                                    // lane = row
    const int wq   = __builtin_amdgcn_readfirstlane(t >> 6);  // wave 0..15

    const int tile0 = blockIdx.x * NTPB;

    // ---- prologue: stage tile0 fully (6 async ops/wave, zero VGPR) ----
    {
        const float* g = x + (size_t)tile0 * TILE_F;
        stage_A(g + wq * APW + lane * 4,       buf + wq * APW,       lane);
        stage_B(g + A_F + wq * BPW + lane * 4, buf + A_F + wq * BPW, lane);
    }
    asm volatile("s_waitcnt vmcnt(0)" ::: "memory");
    __builtin_amdgcn_s_barrier();

    #pragma unroll 1
    for (int it = 0; it < NTPB; ++it) {
        const int tile  = tile0 + it;
        // unconditional staging (static vm-op counts); last iter re-stages the
        // CURRENT tile (just consumed -> likely L2-resident, cheap refetch).
        const int tnext = (it + 1 < NTPB) ? tile + 1 : tile;
        const float* gnext = x + (size_t)tnext * TILE_F;

        // ---- data_t loads FIRST (oldest vm ops of the iteration) ----
        const f32x4* dt4 = (const f32x4*)data_t + (size_t)tile * 1600;
        f32x4 tv0 = dt4[t], tv1;
        if (t < 576) tv1 = dt4[1024 + t];

        // ---- x: my k-sixteenth -> registers ----
        float xk[20];
        {
            const float* xr = buf + row * 310 + wq * 20;
            if (wq == 15) {
                #pragma unroll
                for (int q = 0; q < 5; ++q)
                    *(f32x2*)&xk[2 * q] = *(const f32x2*)(xr + 2 * q);
            } else {
                #pragma unroll
                for (int q = 0; q < 10; ++q)
                    *(f32x2*)&xk[2 * q] = *(const f32x2*)(xr + 2 * q);
            }
        }
        asm volatile("s_waitcnt lgkmcnt(0)" ::: "memory");
        __builtin_amdgcn_s_barrier();     // (a0): buf free (x lives in regs)

        // ---- stage next tile's B region (not scratch-aliased) ----
        stage_B(gnext + A_F + wq * BPW + lane * 4, buf + A_F + wq * BPW, lane);

        // ---- L1: my k-sixteenth, weights via s_load (SGPR broadcast) ----
        float acc[10] = {0,0,0,0,0,0,0,0,0,0};
        if (wq == 15) fma_xk<10>(xk, W1 + 3000, acc);
        else          fma_xk<20>(xk, W1 + wq * 200, acc);

        {   // ---- partials [row][wq][10] into A-region scratch ----
            float* pw = buf + row * PSTR + wq * 10;
            #pragma unroll
            for (int j = 0; j < 5; ++j)
                *(f32x2*)(pw + 2 * j) = (f32x2){acc[2 * j], acc[2 * j + 1]};
        }
        asm volatile("s_waitcnt lgkmcnt(0)" ::: "memory");
        __builtin_amdgcn_s_barrier();     // (a)

        // ---- distributed h1: thread (j=wq<10, row=lane) sums 16 slots ----
        if (wq < 10) {
            const float* pr = buf + row * PSTR + wq;   // + s*10 per slot
            float s = b1[wq];
            #pragma unroll
            for (int sl = 0; sl < 16; ++sl) s += pr[sl * 10];
            buf[H1_OFF + row * H1STR + wq] = leaky(s);
        }
        asm volatile("s_waitcnt lgkmcnt(0)" ::: "memory");
        __builtin_amdgcn_s_barrier();     // (h): h1 ready

        // ---- h1 for my row: 5 x ds_read_b64 ----
        float h1[10];
        {
            const float* hr = buf + H1_OFF + row * H1STR;
            #pragma unroll
            for (int m = 0; m < 5; ++m) {
                f32x2 v = *(const f32x2*)(hr + 2 * m);
                h1[2 * m] = v.x; h1[2 * m + 1] = v.y;
            }
        }

        // ---- L2 j-slice (8 outs) + L3 partial; weights via s_load ----
        float hh[8];
        #pragma unroll
        for (int jj = 0; jj < 8; ++jj) hh[jj] = b2[wq * 8 + jj];
        #pragma unroll
        for (int k = 0; k < 10; ++k) {
            #pragma unroll
            for (int jj = 0; jj < 8; ++jj)
                hh[jj] = fmaf(h1[k], W2[k * 128 + wq * 8 + jj], hh[jj]);
        }
        f32x2 p = {0.f, 0.f};
        #pragma unroll
        for (int jj = 0; jj < 8; ++jj) {
            const float s = leaky(hh[jj]);
            p.x = fmaf(s, W3[(wq * 8 + jj) * 2 + 0], p.x);
            p.y = fmaf(s, W3[(wq * 8 + jj) * 2 + 1], p.y);
        }

        // ---- coeff partials [row][34] at CP_OFF ----
        *(f32x2*)(buf + CP_OFF + row * CPSTR + 2 * wq) = p;
        asm volatile("s_waitcnt lgkmcnt(0)" ::: "memory");
        __builtin_amdgcn_s_barrier();     // (b)

        if (wq == 0) {   // 16 x b64 reads, 16-bank spread
            const float* cb = buf + CP_OFF + row * CPSTR;
            f32x2 q = {b3[0], b3[1]};
            #pragma unroll
            for (int i = 0; i < 16; ++i) {
                f32x2 v = *(const f32x2*)(cb + 2 * i);
                q.x += v.x;
                q.y += v.y;
            }
            *(f32x2*)(ccs + 2 * row) = leaky2(q);
        }
        asm volatile("s_waitcnt lgkmcnt(0)" ::: "memory");
        __builtin_amdgcn_s_barrier();     // (b2): ccs ready, A-scratch dead

        // ---- stage next tile's A region (scratch dead now) ----
        stage_A(gnext + wq * APW + lane * 4, buf + wq * APW, lane);

        // ---- epilogue: out = t*(c0 + c1*t) ----
        f32x4* o4 = (f32x4*)out + (size_t)tile * 1600;
        {
            f32x2 cc = *(const f32x2*)(ccs + 2 * (t / 25));
            o4[t] = tv0 * (tv0 * cc.y + cc.x);
        }
        if (t < 576) {
            const int idx = 1024 + t;
            f32x2 cc = *(const f32x2*)(ccs + 2 * (idx / 25));
            o4[idx] = tv1 * (tv1 * cc.y + cc.x);
        }

        // ---- (d): all 6 staging ops of tile it+1 retired; 1 store rides ----
        asm volatile("s_waitcnt vmcnt(1)" ::: "memory");
        __builtin_amdgcn_s_barrier();
    }
}

extern "C" void kernel_launch(void* const* d_in, const int* in_sizes, int n_in,
                              void* d_out, int out_size, void* d_ws, size_t ws_size,
                              hipStream_t stream) {
    const float* x      = (const float*)d_in[0];
    const float* data_t = (const float*)d_in[1];
    const float* W1     = (const float*)d_in[2];
    const float* b1     = (const float*)d_in[3];
    const float* W2     = (const float*)d_in[4];
    const float* b2     = (const float*)d_in[5];
    const float* W3     = (const float*)d_in[6];
    const float* b3     = (const float*)d_in[7];
    float* out = (float*)d_out;

    hipFuncSetAttribute((const void*)gen_mlp_r18,
                        hipFuncAttributeMaxDynamicSharedMemorySize, LDS_BYTES);
    // 512 blocks x 1024 threads (16 waves) x 4 tiles of 64 rows = 131072 rows;
    // 2 blocks/CU = 32 waves/CU.
    gen_mlp_r18<<<512, 1024, LDS_BYTES, stream>>>(x, data_t, W1, b1, W2, b2, W3, b3, out);
}